// Round 3
// baseline (72.165 us; speedup 1.0000x reference)
//
#include <hip/hip_runtime.h>

// out[i, 0:512]  = 2*X[i]                         (i < 64)
//                = X[i] + sum_{j=i-64}^{i-1} X[j] (i >= 64)
// out[i,512:1024]= X[i]
//
// Pass A: 8-row chunk sums C8[k] = sum of X rows [8k, 8k+8).
// Pass B: one thread per (row, float4-column). Window [i-64, i) with p = i&7,
//         k = i/8 - 8 decomposes into full chunks k+1..k+7 plus 8 boundary
//         rows r_j = 8k + j + (j<p ? 64 : 0), j=0..7. 16 loads, 2 stores,
//         full occupancy (8192 waves).

#define LENS 64
#define C4 128        // float4 columns per X row (512 floats)

__global__ __launch_bounds__(256) void chunk8_kernel(const float4* __restrict__ X4,
                                                     float4* __restrict__ C8,
                                                     int nChunks) {
    const int t  = blockIdx.x * 256 + threadIdx.x;
    const int c4 = t & (C4 - 1);
    const int k  = t >> 7;
    if (k >= nChunks) return;
    const float4* p = X4 + (size_t)k * 8 * C4 + c4;
    float4 s = make_float4(0.f, 0.f, 0.f, 0.f);
#pragma unroll
    for (int j = 0; j < 8; ++j) {
        float4 x = p[(size_t)j * C4];
        s.x += x.x; s.y += x.y; s.z += x.z; s.w += x.w;
    }
    C8[(size_t)k * C4 + c4] = s;
}

__global__ __launch_bounds__(256) void winsum_kernel(const float4* __restrict__ X4,
                                                     const float4* __restrict__ C8,
                                                     float4* __restrict__ O4,
                                                     int N) {
    const int t  = blockIdx.x * 256 + threadIdx.x;
    const int c4 = t & (C4 - 1);
    const int i  = t >> 7;            // row; uniform across each wave
    if (i >= N) return;

    const float4 x = X4[(size_t)i * C4 + c4];

    if (i < LENS) {
        float4 h = make_float4(2.f * x.x, 2.f * x.y, 2.f * x.z, 2.f * x.w);
        O4[(size_t)i * (2 * C4) + c4]      = h;
        O4[(size_t)i * (2 * C4) + C4 + c4] = x;
        return;
    }

    const int p = i & 7;
    const int k = (i >> 3) - 8;

    float4 w = make_float4(0.f, 0.f, 0.f, 0.f);
#pragma unroll
    for (int q = 1; q <= 7; ++q) {
        float4 cs = C8[(size_t)(k + q) * C4 + c4];
        w.x += cs.x; w.y += cs.y; w.z += cs.z; w.w += cs.w;
    }
#pragma unroll
    for (int j = 0; j < 8; ++j) {
        const int r = 8 * k + j + ((j < p) ? 64 : 0);   // boundary rows
        float4 v = X4[(size_t)r * C4 + c4];
        w.x += v.x; w.y += v.y; w.z += v.z; w.w += v.w;
    }

    float4 h = make_float4(x.x + w.x, x.y + w.y, x.z + w.z, x.w + w.w);
    O4[(size_t)i * (2 * C4) + c4]      = h;
    O4[(size_t)i * (2 * C4) + C4 + c4] = x;
}

extern "C" void kernel_launch(void* const* d_in, const int* in_sizes, int n_in,
                              void* d_out, int out_size, void* d_ws, size_t ws_size,
                              hipStream_t stream) {
    const float* X = (const float*)d_in[0];   // (N, 512) fp32; d_in[1]=W is dead code
    float* O = (float*)d_out;                 // (N, 1024) fp32
    float* C = (float*)d_ws;                  // (N/8, 512) chunk sums, 1 MB

    const int D = 512;
    const int N = in_sizes[0] / D;            // 4096
    const int nChunks = N / 8;                // 512

    chunk8_kernel<<<(nChunks * C4 + 255) / 256, 256, 0, stream>>>(
        (const float4*)X, (float4*)C, nChunks);

    winsum_kernel<<<(N * C4 + 255) / 256, 256, 0, stream>>>(
        (const float4*)X, (const float4*)C, (float4*)O, N);
}

// Round 4
// 71.825 us; speedup vs baseline: 1.0047x; 1.0047x over previous
//
#include <hip/hip_runtime.h>

// out[i, 0:512]  = 2*X[i]                         (i < 64)
//                = X[i] + sum_{j=i-64}^{i-1} X[j] (i >= 64)
// out[i,512:1024]= X[i]
//
// Single fused kernel. Block = 256 threads = (c4 in [0,128), g in {0,1}),
// owns 16 rows [r0, r0+16). Step 1: 9 chunk sums (8 rows each) covering
// [r0-64, r0+8) into LDS. Step 2: per-thread sliding window over 8 rows,
// seeded from 8 LDS chunk sums.

#define LENS 64
#define C4 128        // float4 columns per X row (512 floats)

__global__ __launch_bounds__(256) void fused_winsum_kernel(const float4* __restrict__ X4,
                                                           float4* __restrict__ O4,
                                                           int N) {
    __shared__ float4 cs[9 * C4];     // 18 KB

    const int c4 = threadIdx.x & (C4 - 1);
    const int g  = threadIdx.x >> 7;  // 0 or 1: which 8-row group
    const int r0 = blockIdx.x * 16;
    if (r0 >= N) return;

    if (r0 < LENS) {
        // rows 0..63: H = 2X, copy X. (r0 multiple of 16 -> whole block < 64)
#pragma unroll
        for (int k = 0; k < 8; ++k) {
            const int i = r0 + 8 * g + k;
            float4 x = X4[(size_t)i * C4 + c4];
            float4 h = make_float4(2.f * x.x, 2.f * x.y, 2.f * x.z, 2.f * x.w);
            O4[(size_t)i * (2 * C4) + c4]      = h;
            O4[(size_t)i * (2 * C4) + C4 + c4] = x;
        }
        return;
    }

    // Step 1: chunk sums ch=0..8 over rows [r0-64+8*ch, r0-64+8*ch+8)
    for (int ch = g; ch < 9; ch += 2) {
        const float4* p = X4 + (size_t)(r0 - LENS + 8 * ch) * C4 + c4;
        float4 s = make_float4(0.f, 0.f, 0.f, 0.f);
#pragma unroll
        for (int j = 0; j < 8; ++j) {
            float4 x = p[(size_t)j * C4];
            s.x += x.x; s.y += x.y; s.z += x.z; s.w += x.w;
        }
        cs[ch * C4 + c4] = s;
    }
    __syncthreads();

    // Step 2: sliding window over rows [i0, i0+8)
    const int i0 = r0 + 8 * g;
    float4 w = make_float4(0.f, 0.f, 0.f, 0.f);
#pragma unroll
    for (int q = 0; q < 8; ++q) {
        float4 s = cs[(g + q) * C4 + c4];
        w.x += s.x; w.y += s.y; w.z += s.z; w.w += s.w;
    }

    float4 hist[7];
    const float4* ph = X4 + (size_t)(i0 - LENS) * C4 + c4;
#pragma unroll
    for (int j = 0; j < 7; ++j) hist[j] = ph[(size_t)j * C4];   // L1/L2 hot

#pragma unroll
    for (int k = 0; k < 8; ++k) {
        const int i = i0 + k;
        float4 x = X4[(size_t)i * C4 + c4];
        float4 h = make_float4(x.x + w.x, x.y + w.y, x.z + w.z, x.w + w.w);
        O4[(size_t)i * (2 * C4) + c4]      = h;
        O4[(size_t)i * (2 * C4) + C4 + c4] = x;
        if (k < 7) {
            float4 old = hist[k];
            w.x += x.x - old.x;
            w.y += x.y - old.y;
            w.z += x.z - old.z;
            w.w += x.w - old.w;
        }
    }
}

extern "C" void kernel_launch(void* const* d_in, const int* in_sizes, int n_in,
                              void* d_out, int out_size, void* d_ws, size_t ws_size,
                              hipStream_t stream) {
    const float* X = (const float*)d_in[0];   // (N, 512) fp32; d_in[1]=W is dead code
    float* O = (float*)d_out;                 // (N, 1024) fp32

    const int D = 512;
    const int N = in_sizes[0] / D;            // 4096

    fused_winsum_kernel<<<(N + 15) / 16, 256, 0, stream>>>(
        (const float4*)X, (float4*)O, N);
}